// Round 4
// baseline (968.558 us; speedup 1.0000x reference)
//
#include <hip/hip_runtime.h>
#include <hip/hip_bf16.h>

typedef unsigned short u16;
typedef unsigned int   u32;
typedef short bf16x8 __attribute__((ext_vector_type(8)));   // 8 bf16 = 4 VGPRs (MFMA A/B frag)
typedef float f32x4  __attribute__((ext_vector_type(4)));   // MFMA C/D frag

#define N_PTS   524288

// ws layout (u16 element offsets). Grids stored channel-last bf16 (voxel-major, 16ch).
#define WS_TAU   18939904
#define WS_MAP   37879808
#define WS_TMLP  37912576
#define WS_MLP   37928960
#define WS_TOTAL_BYTES (37978112ULL * 2ULL)

// Compiler memory fence: keeps differently-typed LDS reads/writes of the act
// tile from being reordered (TBAA insurance; zero runtime cost).
__device__ __forceinline__ void ldsfence() { __asm__ __volatile__("" ::: "memory"); }

// ---------- bf16 helpers ----------
__device__ __forceinline__ float b2f(u16 b) {
    u32 u = ((u32)b) << 16; float f; __builtin_memcpy(&f, &u, 4); return f;
}
__device__ __forceinline__ u16 f2b(float f) {
    u32 u; __builtin_memcpy(&u, &f, 4);
    u32 r = (u + 0x7FFFu + ((u >> 16) & 1u)) >> 16;   // RNE
    return (u16)r;
}
__device__ __forceinline__ float fsilu(float x) { return x / (1.f + __expf(-x)); }
__device__ __forceinline__ float ftanh(float x) {
    float e = __expf(2.f * x);
    return 1.f - 2.f / (e + 1.f);
}

// act LDS index, XOR swizzle on 16B chunks (breaks 256B power-of-2 row stride).
// Any access within one 8-elem chunk (4- or 8-aligned groups) stays contiguous.
__device__ __forceinline__ int aidx(int row, int ch) {
    return (row << 7) + ((((ch >> 3) ^ (row & 7))) << 3) + (ch & 7);
}

__device__ __forceinline__ void store4(u16* actw, int row, int ch,
                                       float v0, float v1, float v2, float v3) {
    u32 lo = (u32)f2b(v0) | ((u32)f2b(v1) << 16);
    u32 hi = (u32)f2b(v2) | ((u32)f2b(v3) << 16);
    *(uint2*)(actw + aidx(row, ch)) = make_uint2(lo, hi);   // ds_write_b64
}

struct GridPtrs { const float* g[4]; };

// ---------- grid transpose+cvt: f32 (C=16, S^3) -> bf16 (S^3, C=16) ----------
__global__ void dtn_transpose(const float* __restrict__ src, u16* __restrict__ dst, int S3) {
    int v = blockIdx.x * 256 + threadIdx.x;
    if (v >= S3) return;
    u32 packed[8];
#pragma unroll
    for (int c = 0; c < 8; ++c) {
        u32 lo = f2b(src[(2 * c) * S3 + v]);
        u32 hi = f2b(src[(2 * c + 1) * S3 + v]);
        packed[c] = lo | (hi << 16);
    }
    uint4* d = (uint4*)(dst + (long long)v * 16);
    d[0] = make_uint4(packed[0], packed[1], packed[2], packed[3]);
    d[1] = make_uint4(packed[4], packed[5], packed[6], packed[7]);
}

// ---------- f32 -> bf16 weight convert ----------
__global__ void dtn_cvt(const float* __restrict__ src, u16* __restrict__ dst, int n) {
    int i = blockIdx.x * 256 + threadIdx.x;
    if (i < n) dst[i] = f2b(src[i]);
}

// ---------- featurize: 4-level trilinear sample (silu) + 64-ch sin FFM -> 128 bf16 LDS row ----------
template<int USE_WS, int HASB>
__device__ __forceinline__ void featurize(const u16* __restrict__ gT, GridPtrs gp,
                                          float x, float y, float z,
                                          const float* __restrict__ pe_w,
                                          const float* __restrict__ pe_b,
                                          u16* __restrict__ actw, int row)
{
    const int Ss[4]   = {16, 32, 64, 96};
    const int offs[4] = {0, 65536, 589824, 4784128};   // dest offsets (16ch * S^3)
    const int S3s[4]  = {4096, 32768, 262144, 884736};
#pragma unroll
    for (int l = 0; l < 4; ++l) {
        const int S = Ss[l];
        float fS = (float)(S - 1);
        float px = fminf(fmaxf((x + 1.f) * 0.5f * fS, 0.f), fS);
        float py = fminf(fmaxf((y + 1.f) * 0.5f * fS, 0.f), fS);
        float pz = fminf(fmaxf((z + 1.f) * 0.5f * fS, 0.f), fS);
        int ix0 = (int)px, iy0 = (int)py, iz0 = (int)pz;
        float wx = px - (float)ix0, wy = py - (float)iy0, wz = pz - (float)iz0;
        int ix1 = min(ix0 + 1, S - 1), iy1 = min(iy0 + 1, S - 1), iz1 = min(iz0 + 1, S - 1);

        float f[16];
#pragma unroll
        for (int c = 0; c < 16; ++c) f[c] = 0.f;

#pragma unroll
        for (int cz = 0; cz < 2; ++cz) {
            int zz = cz ? iz1 : iz0;
            float wgtz = cz ? wz : (1.f - wz);
#pragma unroll
            for (int cy = 0; cy < 2; ++cy) {
                int yy = cy ? iy1 : iy0;
                float wgty = wgtz * (cy ? wy : (1.f - wy));
#pragma unroll
                for (int cx = 0; cx < 2; ++cx) {
                    int xx = cx ? ix1 : ix0;
                    float wgt = wgty * (cx ? wx : (1.f - wx));
                    if (USE_WS) {
                        const u16* g = gT + offs[l];
                        const uint4* p = (const uint4*)(g + (size_t)(((zz * S) + yy) * S + xx) * 16);
                        uint4 a = p[0], b = p[1];
                        f[0]  += wgt * b2f((u16)(a.x & 0xffff));  f[1]  += wgt * b2f((u16)(a.x >> 16));
                        f[2]  += wgt * b2f((u16)(a.y & 0xffff));  f[3]  += wgt * b2f((u16)(a.y >> 16));
                        f[4]  += wgt * b2f((u16)(a.z & 0xffff));  f[5]  += wgt * b2f((u16)(a.z >> 16));
                        f[6]  += wgt * b2f((u16)(a.w & 0xffff));  f[7]  += wgt * b2f((u16)(a.w >> 16));
                        f[8]  += wgt * b2f((u16)(b.x & 0xffff));  f[9]  += wgt * b2f((u16)(b.x >> 16));
                        f[10] += wgt * b2f((u16)(b.y & 0xffff));  f[11] += wgt * b2f((u16)(b.y >> 16));
                        f[12] += wgt * b2f((u16)(b.z & 0xffff));  f[13] += wgt * b2f((u16)(b.z >> 16));
                        f[14] += wgt * b2f((u16)(b.w & 0xffff));  f[15] += wgt * b2f((u16)(b.w >> 16));
                    } else {
                        const float* gc = gp.g[l];
                        size_t vox = (size_t)((zz * S) + yy) * S + xx;
#pragma unroll
                        for (int c = 0; c < 16; ++c)
                            f[c] += wgt * gc[(size_t)c * S3s[l] + vox];
                    }
                }
            }
        }
#pragma unroll
        for (int c = 0; c < 16; c += 4)
            store4(actw, row, l * 16 + c,
                   fsilu(f[c]), fsilu(f[c + 1]), fsilu(f[c + 2]), fsilu(f[c + 3]));
    }
    // FFM: sin(coords @ pe_w^T (+ b)) -> channels 64..127 (pe_w is f32 (64,3))
#pragma unroll 4
    for (int fc = 0; fc < 64; fc += 4) {
        float s[4];
#pragma unroll
        for (int j = 0; j < 4; ++j) {
            int ch = fc + j;
            float a = x * pe_w[ch * 3 + 0] + y * pe_w[ch * 3 + 1] + z * pe_w[ch * 3 + 2];
            if (HASB) a += pe_b[ch];
            s[j] = __sinf(a);
        }
        store4(actw, row, 64 + fc, s[0], s[1], s[2], s[3]);
    }
}

// ---------- per-wave 128x128 layer: D(out_ch, pt) = W(128x128) x act^T ----------
__device__ __forceinline__ void loadB(const u16* actw, bf16x8 B[4][4], int l16, int quad) {
#pragma unroll
    for (int nt = 0; nt < 4; ++nt)
#pragma unroll
        for (int kt = 0; kt < 4; ++kt)
            B[nt][kt] = *(const bf16x8*)(actw + aidx(nt * 16 + l16, kt * 32 + quad * 8));
    ldsfence();   // pin loads BEFORE the in-place epilogue stores that follow
}

template<int USE_WS>
__device__ __forceinline__ bf16x8 loadA(const u16* WT, const float* Wf, int row, int chunk) {
    if (USE_WS) {
        return ((const bf16x8*)WT)[row * 16 + chunk];
    } else {
        const float4* p = (const float4*)(Wf + row * 128 + chunk * 8);
        float4 f0 = p[0], f1 = p[1];
        u32 w0 = (u32)f2b(f0.x) | ((u32)f2b(f0.y) << 16);
        u32 w1 = (u32)f2b(f0.z) | ((u32)f2b(f0.w) << 16);
        u32 w2 = (u32)f2b(f1.x) | ((u32)f2b(f1.y) << 16);
        u32 w3 = (u32)f2b(f1.z) | ((u32)f2b(f1.w) << 16);
        uint4 packed = make_uint4(w0, w1, w2, w3);
        bf16x8 r; __builtin_memcpy(&r, &packed, 16); return r;
    }
}

template<int USE_WS, typename Epi>
__device__ __forceinline__ void gemm128(const u16* __restrict__ WT, const float* __restrict__ Wf,
                                        const bf16x8 B[4][4],
                                        int l16, int quad, Epi&& epi)
{
#pragma unroll
    for (int mt = 0; mt < 8; ++mt) {
        f32x4 acc[4];
#pragma unroll
        for (int nt = 0; nt < 4; ++nt) acc[nt] = (f32x4){0.f, 0.f, 0.f, 0.f};
#pragma unroll
        for (int kt = 0; kt < 4; ++kt) {
            // A frag: W[mt*16 + (lane&15)][kt*32 + quad*8 .. +7]
            bf16x8 a = loadA<USE_WS>(WT, Wf, mt * 16 + l16, kt * 4 + quad);
#pragma unroll
            for (int nt = 0; nt < 4; ++nt)
                acc[nt] = __builtin_amdgcn_mfma_f32_16x16x32_bf16(a, B[nt][kt], acc[nt], 0, 0, 0);
        }
#pragma unroll
        for (int nt = 0; nt < 4; ++nt) epi(mt, nt, acc[nt]);
    }
}

// ---------- fused main kernel: one block = 256 points, one wave = 64 points ----------
template<int USE_WS>
__global__ void __launch_bounds__(256, 2)
dtn_main(const float* __restrict__ nc, const float* __restrict__ tauP,
         const float* __restrict__ phys, const u16* __restrict__ wsT,
         GridPtrs vgp, GridPtrs tgp,
         const float* __restrict__ vec_pe_w, const float* __restrict__ tau_pe_w,
         const float* __restrict__ tau_pe_b, const float* __restrict__ vscale,
         const float* __restrict__ map_w, const float* __restrict__ tau_mlp_w,
         const float* __restrict__ mlp_w, const float* __restrict__ tau_pars,
         const float* __restrict__ last_w, float* __restrict__ outP)
{
    __shared__ __align__(16) u16 act_s[4][64 * 128];   // 64 KiB, per-wave 64x128 bf16 tiles
    const int tid  = threadIdx.x;
    const int w    = tid >> 6, lane = tid & 63;
    const int quad = lane >> 4, l16 = lane & 15;
    u16* actw = act_s[w];

    const int pBase = blockIdx.x * 256;
    const int myPt  = pBase + tid;        // featurize / final-phase point
    const int wPt0  = pBase + w * 64;     // wave's first point

    float cx = nc[myPt * 3 + 0];
    float cy = nc[myPt * 3 + 1];
    float cz = nc[myPt * 3 + 2];

    float tauv[4];
#pragma unroll
    for (int nt = 0; nt < 4; ++nt) tauv[nt] = tauP[wPt0 + nt * 16 + l16];

    const u16* wsVec = wsT;
    const u16* wsTau = wsT + WS_TAU;
    const u16* wMap  = wsT + WS_MAP;
    const u16* wTmlp = wsT + WS_TMLP;
    const u16* wMlp  = wsT + WS_MLP;

    // ---- tau featurize ----
    featurize<USE_WS, 1>(wsTau, tgp, cx, cy, cz, tau_pe_w, tau_pe_b, actw, lane);
    __syncthreads();

    // ---- tfp = tau_features @ tau_mlp_w^T  (packed bf16 in regs, C-frag layout) ----
    bf16x8 B[4][4];
    loadB(actw, B, l16, quad);
    u32 tfpPk[64];
    gemm128<USE_WS>(wTmlp, tau_mlp_w, B, l16, quad, [&](int mt, int nt, f32x4 acc) {
        int base = (mt * 4 + nt) * 2;
        tfpPk[base + 0] = (u32)f2b(acc[0]) | ((u32)f2b(acc[1]) << 16);
        tfpPk[base + 1] = (u32)f2b(acc[2]) | ((u32)f2b(acc[3]) << 16);
    });
    __syncthreads();

    // ---- vec featurize (overwrite act) ----
    featurize<USE_WS, 0>(wsVec, vgp, cx, cy, cz, vec_pe_w, (const float*)nullptr, actw, lane);
    __syncthreads();

    // ---- vec_map layer 0: act = silu(act @ W0^T) ----
    loadB(actw, B, l16, quad);
    gemm128<USE_WS>(wMap, map_w, B, l16, quad, [&](int mt, int nt, f32x4 acc) {
        int cb = mt * 16 + quad * 4, pt = nt * 16 + l16;
        store4(actw, pt, cb, fsilu(acc[0]), fsilu(acc[1]), fsilu(acc[2]), fsilu(acc[3]));
    });
    __syncthreads();

    // ---- vec_map layer 1 fused with out-init: act = tanh(tau * vscale * silu(.)) ----
    loadB(actw, B, l16, quad);
    gemm128<USE_WS>(wMap + 128 * 128, map_w + 128 * 128, B, l16, quad, [&](int mt, int nt, f32x4 acc) {
        int cb = mt * 16 + quad * 4, pt = nt * 16 + l16;
        float t = tauv[nt];
        float s0 = vscale[cb + 0], s1 = vscale[cb + 1], s2 = vscale[cb + 2], s3 = vscale[cb + 3];
        store4(actw, pt, cb,
               ftanh(t * s0 * fsilu(acc[0])), ftanh(t * s1 * fsilu(acc[1])),
               ftanh(t * s2 * fsilu(acc[2])), ftanh(t * s3 * fsilu(acc[3])));
    });
    __syncthreads();

    // ---- 3 residual layers: out += tanh(tau*tp) * silu(out @ Wv^T [* tfp @ idx0]) ----
#pragma unroll
    for (int idx = 0; idx < 3; ++idx) {
        loadB(actw, B, l16, quad);
        gemm128<USE_WS>(wMlp + idx * 128 * 128, mlp_w + idx * 128 * 128, B, l16, quad,
                        [&](int mt, int nt, f32x4 acc) {
            int cb = mt * 16 + quad * 4, pt = nt * 16 + l16;
            float t = tauv[nt];
            const float* tp = tau_pars + idx * 128;
            uint2 old = *(const uint2*)(actw + aidx(pt, cb));
            float h0 = acc[0], h1 = acc[1], h2 = acc[2], h3 = acc[3];
            if (idx == 0) {
                int base = (mt * 4 + nt) * 2;
                h0 *= b2f((u16)(tfpPk[base] & 0xffff));
                h1 *= b2f((u16)(tfpPk[base] >> 16));
                h2 *= b2f((u16)(tfpPk[base + 1] & 0xffff));
                h3 *= b2f((u16)(tfpPk[base + 1] >> 16));
            }
            float n0 = b2f((u16)(old.x & 0xffff)) + ftanh(t * tp[cb + 0]) * fsilu(h0);
            float n1 = b2f((u16)(old.x >> 16))    + ftanh(t * tp[cb + 1]) * fsilu(h1);
            float n2 = b2f((u16)(old.y & 0xffff)) + ftanh(t * tp[cb + 2]) * fsilu(h2);
            float n3 = b2f((u16)(old.y >> 16))    + ftanh(t * tp[cb + 3]) * fsilu(h3);
            store4(actw, pt, cb, n0, n1, n2, n3);
        });
        __syncthreads();
    }

    // ---- head: out = physical + act_row @ last_w^T  (3x128, per-thread VALU, f32 OUT) ----
    float a0 = 0.f, a1 = 0.f, a2 = 0.f;
#pragma unroll
    for (int c8 = 0; c8 < 16; ++c8) {
        bf16x8 v = *(const bf16x8*)(actw + aidx(lane, c8 * 8));
        const u16* vp = (const u16*)&v;
#pragma unroll
        for (int j = 0; j < 8; ++j) {
            float av = b2f(vp[j]);
            int k = c8 * 8 + j;
            a0 += av * last_w[0 * 128 + k];
            a1 += av * last_w[1 * 128 + k];
            a2 += av * last_w[2 * 128 + k];
        }
    }
    // Reference output is float32 (physical + out@last_w.T, all-f32 graph).
    outP[myPt * 3 + 0] = phys[myPt * 3 + 0] + a0;
    outP[myPt * 3 + 1] = phys[myPt * 3 + 1] + a1;
    outP[myPt * 3 + 2] = phys[myPt * 3 + 2] + a2;
}

// ---------- launch ----------
extern "C" void kernel_launch(void* const* d_in, const int* in_sizes, int n_in,
                              void* d_out, int out_size, void* d_ws, size_t ws_size,
                              hipStream_t stream)
{
    // Supports both documented dict order (grids interleaved vec_g0,tau_g0,...)
    // and reference-signature order (vec_g0..3 then tau_g0..3). Slots 0-2 and
    // 11-19 are identical in both. Detect via in_sizes[4]: 65536 -> interleaved.
    const float* phys     = (const float*)d_in[0];
    const float* nc       = (const float*)d_in[1];
    const float* tau      = (const float*)d_in[2];
    GridPtrs vgp, tgp;
    bool interleaved = (in_sizes[4] == 65536);
    for (int l = 0; l < 4; ++l) {
        if (interleaved) {
            vgp.g[l] = (const float*)d_in[3 + 2 * l];
            tgp.g[l] = (const float*)d_in[4 + 2 * l];
        } else {
            vgp.g[l] = (const float*)d_in[3 + l];
            tgp.g[l] = (const float*)d_in[7 + l];
        }
    }
    const float* vec_pe_w = (const float*)d_in[11];
    const float* tau_pe_w = (const float*)d_in[12];
    const float* tau_pe_b = (const float*)d_in[13];
    const float* vscale   = (const float*)d_in[14];
    const float* map_w    = (const float*)d_in[15];
    const float* tau_mlp  = (const float*)d_in[16];
    const float* mlp_w    = (const float*)d_in[17];
    const float* tau_pars = (const float*)d_in[18];
    const float* last_w   = (const float*)d_in[19];
    u16* wsT = (u16*)d_ws;

    bool useWs = (ws_size >= WS_TOTAL_BYTES);
    if (useWs) {
        const int S3s[4]  = {4096, 32768, 262144, 884736};
        const int offs[4] = {0, 65536, 589824, 4784128};
        for (int l = 0; l < 4; ++l) {
            dtn_transpose<<<(S3s[l] + 255) / 256, 256, 0, stream>>>(vgp.g[l], wsT + offs[l], S3s[l]);
            dtn_transpose<<<(S3s[l] + 255) / 256, 256, 0, stream>>>(tgp.g[l], wsT + WS_TAU + offs[l], S3s[l]);
        }
        dtn_cvt<<<(32768 + 255) / 256, 256, 0, stream>>>(map_w,   wsT + WS_MAP,  32768);
        dtn_cvt<<<(16384 + 255) / 256, 256, 0, stream>>>(tau_mlp, wsT + WS_TMLP, 16384);
        dtn_cvt<<<(49152 + 255) / 256, 256, 0, stream>>>(mlp_w,   wsT + WS_MLP,  49152);
        dtn_main<1><<<N_PTS / 256, 256, 0, stream>>>(nc, tau, phys, wsT, vgp, tgp,
                                                     vec_pe_w, tau_pe_w, tau_pe_b, vscale,
                                                     map_w, tau_mlp, mlp_w, tau_pars, last_w,
                                                     (float*)d_out);
    } else {
        dtn_main<0><<<N_PTS / 256, 256, 0, stream>>>(nc, tau, phys, wsT, vgp, tgp,
                                                     vec_pe_w, tau_pe_w, tau_pe_b, vscale,
                                                     map_w, tau_mlp, mlp_w, tau_pars, last_w,
                                                     (float*)d_out);
    }
}

// Round 5
// 832.756 us; speedup vs baseline: 1.1631x; 1.1631x over previous
//
#include <hip/hip_runtime.h>
#include <hip/hip_bf16.h>

typedef unsigned short u16;
typedef unsigned int   u32;
typedef short bf16x8 __attribute__((ext_vector_type(8)));   // 8 bf16 = 4 VGPRs (MFMA A/B frag)
typedef float f32x4  __attribute__((ext_vector_type(4)));   // MFMA C/D frag

#define N_PTS   524288

// ws layout (u16 element offsets). Grids stored channel-last bf16 (voxel-major, 16ch).
#define WS_TAU   18939904
#define WS_MAP   37879808
#define WS_TMLP  37912576
#define WS_MLP   37928960
#define WS_TOTAL_BYTES (37978112ULL * 2ULL)

// Compiler memory fence: keeps differently-typed LDS reads/writes of the act
// tile from being reordered (TBAA insurance; zero runtime cost).
__device__ __forceinline__ void ldsfence() { __asm__ __volatile__("" ::: "memory"); }

// ---------- bf16 / fast-math helpers ----------
__device__ __forceinline__ float b2f(u16 b) {
    u32 u = ((u32)b) << 16; float f; __builtin_memcpy(&f, &u, 4); return f;
}
__device__ __forceinline__ u16 f2b(float f) {
    u32 u; __builtin_memcpy(&u, &f, 4);
    u32 r = (u + 0x7FFFu + ((u >> 16) & 1u)) >> 16;   // RNE
    return (u16)r;
}
// v_rcp_f32: ~1ulp approx — fine at our 2% tolerance, replaces ~10-inst IEEE div
__device__ __forceinline__ float frcp(float x) { return __builtin_amdgcn_rcpf(x); }
__device__ __forceinline__ float fsilu(float x) { return x * frcp(1.f + __expf(-x)); }
__device__ __forceinline__ float ftanh(float x) {
    float e = __expf(2.f * x);
    return 1.f - 2.f * frcp(e + 1.f);
}
// v_sin_f32 takes revolutions; |arg| <= ~7 rad = 1.2 rev here (well in range)
__device__ __forceinline__ float fsin(float a) {
    return __builtin_amdgcn_sinf(a * 0.15915494309189535f);
}

// act LDS index, XOR swizzle on 16B chunks (breaks 256B power-of-2 row stride).
// Any access within one 8-elem chunk (4- or 8-aligned groups) stays contiguous.
__device__ __forceinline__ int aidx(int row, int ch) {
    return (row << 7) + ((((ch >> 3) ^ (row & 7))) << 3) + (ch & 7);
}

__device__ __forceinline__ void store4(u16* actw, int row, int ch,
                                       float v0, float v1, float v2, float v3) {
    u32 lo = (u32)f2b(v0) | ((u32)f2b(v1) << 16);
    u32 hi = (u32)f2b(v2) | ((u32)f2b(v3) << 16);
    *(uint2*)(actw + aidx(row, ch)) = make_uint2(lo, hi);   // ds_write_b64
}

struct GridPtrs { const float* g[4]; };

// ---------- fused prep: 8 grid transposes (f32 C-major -> bf16 channel-last) + 3 weight cvts ----------
struct PrepArgs {
    const float* vg[4]; const float* tg[4];
    const float* map_w; const float* tmlp; const float* mlp;
    u16* ws;
};
#define PREP_VOXB 9248   // 2*1183744 / 256
__global__ void __launch_bounds__(256) dtn_prep(PrepArgs p) {
    int b = blockIdx.x;
    if (b < PREP_VOXB) {
        int v = b * 256 + threadIdx.x;          // global voxel id over both grid sets
        int set = (v >= 1183744) ? 1 : 0;
        int lv = v - set * 1183744;
        int l, base, S3, off;
        if      (lv <   4096) { l = 0; base = 0;      S3 = 4096;   off = 0;       }
        else if (lv <  36864) { l = 1; base = 4096;   S3 = 32768;  off = 65536;   }
        else if (lv < 299008) { l = 2; base = 36864;  S3 = 262144; off = 589824;  }
        else                  { l = 3; base = 299008; S3 = 884736; off = 4784128; }
        int vox = lv - base;
        const float* src = set ? p.tg[l] : p.vg[l];
        u16* dst = p.ws + (set ? WS_TAU : 0) + off + (size_t)vox * 16;
        u32 packed[8];
#pragma unroll
        for (int c = 0; c < 8; ++c) {
            u32 lo = f2b(src[(2 * c) * S3 + vox]);
            u32 hi = f2b(src[(2 * c + 1) * S3 + vox]);
            packed[c] = lo | (hi << 16);
        }
        uint4* d = (uint4*)dst;
        d[0] = make_uint4(packed[0], packed[1], packed[2], packed[3]);
        d[1] = make_uint4(packed[4], packed[5], packed[6], packed[7]);
    } else {
        int i = (b - PREP_VOXB) * 256 + threadIdx.x;   // weights: 98304 elems total
        if (i < 32768)      p.ws[WS_MAP  + i]          = f2b(p.map_w[i]);
        else if (i < 49152) p.ws[WS_TMLP + (i - 32768)] = f2b(p.tmlp[i - 32768]);
        else if (i < 98304) p.ws[WS_MLP  + (i - 49152)] = f2b(p.mlp[i - 49152]);
    }
}

// ---------- featurize: 4-level trilinear sample (silu) + 64-ch sin FFM -> 128 bf16 LDS row ----------
template<int USE_WS, int HASB>
__device__ __forceinline__ void featurize(const u16* __restrict__ gT, GridPtrs gp,
                                          float x, float y, float z,
                                          const float* __restrict__ pe_w,
                                          const float* __restrict__ pe_b,
                                          u16* __restrict__ actw, int row)
{
    const int Ss[4]   = {16, 32, 64, 96};
    const int offs[4] = {0, 65536, 589824, 4784128};   // dest offsets (16ch * S^3)
    const int S3s[4]  = {4096, 32768, 262144, 884736};
#pragma unroll
    for (int l = 0; l < 4; ++l) {
        const int S = Ss[l];
        float fS = (float)(S - 1);
        float px = fminf(fmaxf((x + 1.f) * 0.5f * fS, 0.f), fS);
        float py = fminf(fmaxf((y + 1.f) * 0.5f * fS, 0.f), fS);
        float pz = fminf(fmaxf((z + 1.f) * 0.5f * fS, 0.f), fS);
        int ix0 = (int)px, iy0 = (int)py, iz0 = (int)pz;
        float wx = px - (float)ix0, wy = py - (float)iy0, wz = pz - (float)iz0;
        int ix1 = min(ix0 + 1, S - 1), iy1 = min(iy0 + 1, S - 1), iz1 = min(iz0 + 1, S - 1);

        float f[16];
#pragma unroll
        for (int c = 0; c < 16; ++c) f[c] = 0.f;

#pragma unroll
        for (int cz = 0; cz < 2; ++cz) {
            int zz = cz ? iz1 : iz0;
            float wgtz = cz ? wz : (1.f - wz);
#pragma unroll
            for (int cy = 0; cy < 2; ++cy) {
                int yy = cy ? iy1 : iy0;
                float wgty = wgtz * (cy ? wy : (1.f - wy));
#pragma unroll
                for (int cx = 0; cx < 2; ++cx) {
                    int xx = cx ? ix1 : ix0;
                    float wgt = wgty * (cx ? wx : (1.f - wx));
                    if (USE_WS) {
                        const u16* g = gT + offs[l];
                        const uint4* p = (const uint4*)(g + (size_t)(((zz * S) + yy) * S + xx) * 16);
                        uint4 a = p[0], b = p[1];
                        f[0]  += wgt * b2f((u16)(a.x & 0xffff));  f[1]  += wgt * b2f((u16)(a.x >> 16));
                        f[2]  += wgt * b2f((u16)(a.y & 0xffff));  f[3]  += wgt * b2f((u16)(a.y >> 16));
                        f[4]  += wgt * b2f((u16)(a.z & 0xffff));  f[5]  += wgt * b2f((u16)(a.z >> 16));
                        f[6]  += wgt * b2f((u16)(a.w & 0xffff));  f[7]  += wgt * b2f((u16)(a.w >> 16));
                        f[8]  += wgt * b2f((u16)(b.x & 0xffff));  f[9]  += wgt * b2f((u16)(b.x >> 16));
                        f[10] += wgt * b2f((u16)(b.y & 0xffff));  f[11] += wgt * b2f((u16)(b.y >> 16));
                        f[12] += wgt * b2f((u16)(b.z & 0xffff));  f[13] += wgt * b2f((u16)(b.z >> 16));
                        f[14] += wgt * b2f((u16)(b.w & 0xffff));  f[15] += wgt * b2f((u16)(b.w >> 16));
                    } else {
                        const float* gc = gp.g[l];
                        size_t vox = (size_t)((zz * S) + yy) * S + xx;
#pragma unroll
                        for (int c = 0; c < 16; ++c)
                            f[c] += wgt * gc[(size_t)c * S3s[l] + vox];
                    }
                }
            }
        }
#pragma unroll
        for (int c = 0; c < 16; c += 4)
            store4(actw, row, l * 16 + c,
                   fsilu(f[c]), fsilu(f[c + 1]), fsilu(f[c + 2]), fsilu(f[c + 3]));
    }
    // FFM: sin(coords @ pe_w^T (+ b)) -> channels 64..127 (pe_w is f32 (64,3))
#pragma unroll 4
    for (int fc = 0; fc < 64; fc += 4) {
        float s[4];
#pragma unroll
        for (int j = 0; j < 4; ++j) {
            int ch = fc + j;
            float a = x * pe_w[ch * 3 + 0] + y * pe_w[ch * 3 + 1] + z * pe_w[ch * 3 + 2];
            if (HASB) a += pe_b[ch];
            s[j] = fsin(a);
        }
        store4(actw, row, 64 + fc, s[0], s[1], s[2], s[3]);
    }
}

// ---------- per-wave 128x128 layer: D(out_ch, pt) = W(128x128) x act^T ----------
__device__ __forceinline__ void loadB(const u16* actw, bf16x8 B[4][4], int l16, int quad) {
#pragma unroll
    for (int nt = 0; nt < 4; ++nt)
#pragma unroll
        for (int kt = 0; kt < 4; ++kt)
            B[nt][kt] = *(const bf16x8*)(actw + aidx(nt * 16 + l16, kt * 32 + quad * 8));
    ldsfence();   // pin loads BEFORE the in-place epilogue stores that follow
}

template<int USE_WS>
__device__ __forceinline__ bf16x8 loadA(const u16* WT, const float* Wf, int row, int chunk) {
    if (USE_WS) {
        return ((const bf16x8*)WT)[row * 16 + chunk];
    } else {
        const float4* p = (const float4*)(Wf + row * 128 + chunk * 8);
        float4 f0 = p[0], f1 = p[1];
        u32 w0 = (u32)f2b(f0.x) | ((u32)f2b(f0.y) << 16);
        u32 w1 = (u32)f2b(f0.z) | ((u32)f2b(f0.w) << 16);
        u32 w2 = (u32)f2b(f1.x) | ((u32)f2b(f1.y) << 16);
        u32 w3 = (u32)f2b(f1.z) | ((u32)f2b(f1.w) << 16);
        uint4 packed = make_uint4(w0, w1, w2, w3);
        bf16x8 r; __builtin_memcpy(&r, &packed, 16); return r;
    }
}

template<int USE_WS, typename Epi>
__device__ __forceinline__ void gemm128(const u16* __restrict__ WT, const float* __restrict__ Wf,
                                        const bf16x8 B[4][4],
                                        int l16, int quad, Epi&& epi)
{
#pragma unroll
    for (int mt = 0; mt < 8; ++mt) {
        f32x4 acc[4];
#pragma unroll
        for (int nt = 0; nt < 4; ++nt) acc[nt] = (f32x4){0.f, 0.f, 0.f, 0.f};
#pragma unroll
        for (int kt = 0; kt < 4; ++kt) {
            // A frag: W[mt*16 + (lane&15)][kt*32 + quad*8 .. +7]
            bf16x8 a = loadA<USE_WS>(WT, Wf, mt * 16 + l16, kt * 4 + quad);
#pragma unroll
            for (int nt = 0; nt < 4; ++nt)
                acc[nt] = __builtin_amdgcn_mfma_f32_16x16x32_bf16(a, B[nt][kt], acc[nt], 0, 0, 0);
        }
#pragma unroll
        for (int nt = 0; nt < 4; ++nt) epi(mt, nt, acc[nt]);
    }
}

// ---------- fused main kernel: one block = one wave = 64 points ----------
// 64-thread blocks: 16 KiB LDS/block -> 10 blocks/CU (31% occ, vs 23% at 256thr/64KiB),
// single-wave barriers are near-free, VGPR capped at 128 by launch_bounds(64,4).
template<int USE_WS>
__global__ void __launch_bounds__(64, 4)
dtn_main(const float* __restrict__ nc, const float* __restrict__ tauP,
         const float* __restrict__ phys, const u16* __restrict__ wsT,
         GridPtrs vgp, GridPtrs tgp,
         const float* __restrict__ vec_pe_w, const float* __restrict__ tau_pe_w,
         const float* __restrict__ tau_pe_b, const float* __restrict__ vscale,
         const float* __restrict__ map_w, const float* __restrict__ tau_mlp_w,
         const float* __restrict__ mlp_w, const float* __restrict__ tau_pars,
         const float* __restrict__ last_w, float* __restrict__ outP)
{
    __shared__ __align__(16) u16 actw[64 * 128];   // 16 KiB, one 64x128 bf16 tile
    const int lane = threadIdx.x;
    const int quad = lane >> 4, l16 = lane & 15;

    const int pBase = blockIdx.x * 64;
    const int myPt  = pBase + lane;

    float cx = nc[myPt * 3 + 0];
    float cy = nc[myPt * 3 + 1];
    float cz = nc[myPt * 3 + 2];

    float tauv[4];
#pragma unroll
    for (int nt = 0; nt < 4; ++nt) tauv[nt] = tauP[pBase + nt * 16 + l16];

    const u16* wsVec = wsT;
    const u16* wsTau = wsT + WS_TAU;
    const u16* wMap  = wsT + WS_MAP;
    const u16* wTmlp = wsT + WS_TMLP;
    const u16* wMlp  = wsT + WS_MLP;

    // ---- tau featurize ----
    featurize<USE_WS, 1>(wsTau, tgp, cx, cy, cz, tau_pe_w, tau_pe_b, actw, lane);
    __syncthreads();

    // ---- tfp = tau_features @ tau_mlp_w^T  (packed bf16 in regs, C-frag layout) ----
    bf16x8 B[4][4];
    loadB(actw, B, l16, quad);
    u32 tfpPk[64];
    gemm128<USE_WS>(wTmlp, tau_mlp_w, B, l16, quad, [&](int mt, int nt, f32x4 acc) {
        int base = (mt * 4 + nt) * 2;
        tfpPk[base + 0] = (u32)f2b(acc[0]) | ((u32)f2b(acc[1]) << 16);
        tfpPk[base + 1] = (u32)f2b(acc[2]) | ((u32)f2b(acc[3]) << 16);
    });
    __syncthreads();

    // ---- vec featurize (overwrite act) ----
    featurize<USE_WS, 0>(wsVec, vgp, cx, cy, cz, vec_pe_w, (const float*)nullptr, actw, lane);
    __syncthreads();

    // ---- vec_map layer 0: act = silu(act @ W0^T) ----
    loadB(actw, B, l16, quad);
    gemm128<USE_WS>(wMap, map_w, B, l16, quad, [&](int mt, int nt, f32x4 acc) {
        int cb = mt * 16 + quad * 4, pt = nt * 16 + l16;
        store4(actw, pt, cb, fsilu(acc[0]), fsilu(acc[1]), fsilu(acc[2]), fsilu(acc[3]));
    });
    __syncthreads();

    // ---- vec_map layer 1 fused with out-init: act = tanh(tau * vscale * silu(.)) ----
    loadB(actw, B, l16, quad);
    gemm128<USE_WS>(wMap + 128 * 128, map_w + 128 * 128, B, l16, quad, [&](int mt, int nt, f32x4 acc) {
        int cb = mt * 16 + quad * 4, pt = nt * 16 + l16;
        float t = tauv[nt];
        float4 vs = *(const float4*)(vscale + cb);
        store4(actw, pt, cb,
               ftanh(t * vs.x * fsilu(acc[0])), ftanh(t * vs.y * fsilu(acc[1])),
               ftanh(t * vs.z * fsilu(acc[2])), ftanh(t * vs.w * fsilu(acc[3])));
    });
    __syncthreads();

    // ---- 3 residual layers: out += tanh(tau*tp) * silu(out @ Wv^T [* tfp @ idx0]) ----
#pragma unroll
    for (int idx = 0; idx < 3; ++idx) {
        loadB(actw, B, l16, quad);
        gemm128<USE_WS>(wMlp + idx * 128 * 128, mlp_w + idx * 128 * 128, B, l16, quad,
                        [&](int mt, int nt, f32x4 acc) {
            int cb = mt * 16 + quad * 4, pt = nt * 16 + l16;
            float t = tauv[nt];
            float4 tp = *(const float4*)(tau_pars + idx * 128 + cb);
            uint2 old = *(const uint2*)(actw + aidx(pt, cb));
            float h0 = acc[0], h1 = acc[1], h2 = acc[2], h3 = acc[3];
            if (idx == 0) {
                int base = (mt * 4 + nt) * 2;
                h0 *= b2f((u16)(tfpPk[base] & 0xffff));
                h1 *= b2f((u16)(tfpPk[base] >> 16));
                h2 *= b2f((u16)(tfpPk[base + 1] & 0xffff));
                h3 *= b2f((u16)(tfpPk[base + 1] >> 16));
            }
            float n0 = b2f((u16)(old.x & 0xffff)) + ftanh(t * tp.x) * fsilu(h0);
            float n1 = b2f((u16)(old.x >> 16))    + ftanh(t * tp.y) * fsilu(h1);
            float n2 = b2f((u16)(old.y & 0xffff)) + ftanh(t * tp.z) * fsilu(h2);
            float n3 = b2f((u16)(old.y >> 16))    + ftanh(t * tp.w) * fsilu(h3);
            store4(actw, pt, cb, n0, n1, n2, n3);
        });
        __syncthreads();
    }

    // ---- head: out = physical + act_row @ last_w^T  (3x128, per-thread VALU, f32 OUT) ----
    float a0 = 0.f, a1 = 0.f, a2 = 0.f;
#pragma unroll
    for (int c8 = 0; c8 < 16; ++c8) {
        bf16x8 v = *(const bf16x8*)(actw + aidx(lane, c8 * 8));
        const u16* vp = (const u16*)&v;
#pragma unroll
        for (int j = 0; j < 8; ++j) {
            float av = b2f(vp[j]);
            int k = c8 * 8 + j;
            a0 += av * last_w[0 * 128 + k];
            a1 += av * last_w[1 * 128 + k];
            a2 += av * last_w[2 * 128 + k];
        }
    }
    outP[myPt * 3 + 0] = phys[myPt * 3 + 0] + a0;
    outP[myPt * 3 + 1] = phys[myPt * 3 + 1] + a1;
    outP[myPt * 3 + 2] = phys[myPt * 3 + 2] + a2;
}

// ---------- launch ----------
extern "C" void kernel_launch(void* const* d_in, const int* in_sizes, int n_in,
                              void* d_out, int out_size, void* d_ws, size_t ws_size,
                              hipStream_t stream)
{
    // Supports both documented dict order (grids interleaved vec_g0,tau_g0,...)
    // and reference-signature order (vec_g0..3 then tau_g0..3). Slots 0-2 and
    // 11-19 are identical in both. Detect via in_sizes[4]: 65536 -> interleaved.
    const float* phys     = (const float*)d_in[0];
    const float* nc       = (const float*)d_in[1];
    const float* tau      = (const float*)d_in[2];
    GridPtrs vgp, tgp;
    bool interleaved = (in_sizes[4] == 65536);
    for (int l = 0; l < 4; ++l) {
        if (interleaved) {
            vgp.g[l] = (const float*)d_in[3 + 2 * l];
            tgp.g[l] = (const float*)d_in[4 + 2 * l];
        } else {
            vgp.g[l] = (const float*)d_in[3 + l];
            tgp.g[l] = (const float*)d_in[7 + l];
        }
    }
    const float* vec_pe_w = (const float*)d_in[11];
    const float* tau_pe_w = (const float*)d_in[12];
    const float* tau_pe_b = (const float*)d_in[13];
    const float* vscale   = (const float*)d_in[14];
    const float* map_w    = (const float*)d_in[15];
    const float* tau_mlp  = (const float*)d_in[16];
    const float* mlp_w    = (const float*)d_in[17];
    const float* tau_pars = (const float*)d_in[18];
    const float* last_w   = (const float*)d_in[19];
    u16* wsT = (u16*)d_ws;

    bool useWs = (ws_size >= WS_TOTAL_BYTES);
    if (useWs) {
        PrepArgs pa;
        for (int l = 0; l < 4; ++l) { pa.vg[l] = vgp.g[l]; pa.tg[l] = tgp.g[l]; }
        pa.map_w = map_w; pa.tmlp = tau_mlp; pa.mlp = mlp_w; pa.ws = wsT;
        dtn_prep<<<PREP_VOXB + 384, 256, 0, stream>>>(pa);
        dtn_main<1><<<N_PTS / 64, 64, 0, stream>>>(nc, tau, phys, wsT, vgp, tgp,
                                                   vec_pe_w, tau_pe_w, tau_pe_b, vscale,
                                                   map_w, tau_mlp, mlp_w, tau_pars, last_w,
                                                   (float*)d_out);
    } else {
        dtn_main<0><<<N_PTS / 64, 64, 0, stream>>>(nc, tau, phys, wsT, vgp, tgp,
                                                   vec_pe_w, tau_pe_w, tau_pe_b, vscale,
                                                   map_w, tau_mlp, mlp_w, tau_pars, last_w,
                                                   (float*)d_out);
    }
}